// Round 6
// baseline (186.200 us; speedup 1.0000x reference)
//
#include <hip/hip_runtime.h>

typedef short short8 __attribute__((ext_vector_type(8)));
typedef float f32x4 __attribute__((ext_vector_type(4)));

#define AS1 __attribute__((address_space(1)))
#define AS3 __attribute__((address_space(3)))

__device__ __forceinline__ void gload16(const void* g, void* l) {
    __builtin_amdgcn_global_load_lds((const AS1 unsigned int*)g, (AS3 unsigned int*)l, 16, 0, 0);
}

__device__ __forceinline__ unsigned short f2bf(float f) {
    union { float f; unsigned u; } c; c.f = f;
    unsigned r = (c.u + 0x7FFFu + ((c.u >> 16) & 1u)) >> 16;
    return (unsigned short)r;
}

__device__ __forceinline__ unsigned cvtpk(float a, float b) {
    unsigned r;
    asm("v_cvt_pk_bf16_f32 %0, %1, %2" : "=v"(r) : "v"(a), "v"(b));
    return r;
}

__device__ __forceinline__ void mfma16(f32x4& d, short8 a, short8 b) {
    asm("v_mfma_f32_16x16x32_bf16 %0, %1, %2, %0" : "+v"(d) : "v"(a), "v"(b));
}

template <int N>
__device__ __forceinline__ void vmwait() {
    if constexpr (N == 0) asm volatile("s_waitcnt vmcnt(0)" ::: "memory");
    else if constexpr (N == 3) asm volatile("s_waitcnt vmcnt(3)" ::: "memory");
    else if constexpr (N == 4) asm volatile("s_waitcnt vmcnt(4)" ::: "memory");
}

// q pre-scale: 1/sqrt(64) * log2(e) -> softmax via exp2
#define QSCALE 0.18033688011112042f

// ---------------- fp32 -> bf16 convert ----------------
__global__ __launch_bounds__(256) void cvt_f32_bf16(const float* __restrict__ in,
                                                    unsigned short* __restrict__ out, int n4) {
    int idx = blockIdx.x * 256 + threadIdx.x;
    int stride = gridDim.x * 256;
    for (int i = idx; i < n4; i += stride) {
        float4 v = ((const float4*)in)[i];
        ushort4 o;
        o.x = f2bf(v.x); o.y = f2bf(v.y); o.z = f2bf(v.z); o.w = f2bf(v.w);
        ((ushort4*)out)[i] = o;
    }
}

// ---------------- BMx256 NT GEMM, half-tile counted-vmcnt pipeline ----------------
// MFR=8 -> BM=256, MFR=4 -> BM=128. 512 thr = 8 waves (2M x 4N), wave tile (MFR*16)x64.
// LDS: As[2buf][2ks][MFR*32][32], Bs[2buf][2ks][256][32] bf16.
// Swizzle: 16B-chunk c' = c ^ ((row>>1)&3), both-sides (pre-swizzled global source).
// Half-tile = one k-slice (32) of A+B. Stage H(t+1,ks0)@ph0, H(t+1,ks1)@ph2.
// Waits: vmcnt(LPH) at ph1-end (completes H(t,ks1)) and ph3-end (completes H(t+1,ks0)).
// Queue never drains below LPH except final tile.
template <int EPI, int MFR>
__global__ __launch_bounds__(512, 2) void gemm256(
    const unsigned short* __restrict__ A, const unsigned short* __restrict__ B,
    const float* __restrict__ bias, int K, int NTN, int N,
    float* __restrict__ Cf, unsigned short* __restrict__ qb,
    unsigned short* __restrict__ kb, unsigned short* __restrict__ vtb) {
    extern __shared__ unsigned short lds[];
    constexpr int AHALF = MFR * 1024;         // elems per A ks-half
    constexpr int ABUF = 2 * AHALF;           // elems per A buffer
    constexpr int LPH = MFR / 4 + 2;          // staging loads per half-tile
    unsigned short* As = lds;                 // [2][2][MFR*32][32]
    unsigned short* Bs = lds + 2 * ABUF;      // [2][2][256][32]

    const int tid = threadIdx.x;
    const int lane = tid & 63;
    const int wid = tid >> 6;
    const int lr = lane & 15, lg = lane >> 4;
    const int xr = (lr >> 1) & 3;
    const int wm = (wid >> 2) * (MFR * 16);
    const int wn = (wid & 3) * 64;

    const int cpx = gridDim.x >> 3;           // grid % 8 == 0
    const int wg = blockIdx.x;
    const int sw = (wg & 7) * cpx + (wg >> 3);
    const int m0 = (sw / NTN) * (MFR * 32);
    const int n0 = (sw % NTN) * 256;

    // staging: thread -> phys (row = j*128 + tid>>2, chunk = tid&3); source col
    // pre-swizzled: global chunk = (tid&3) ^ ((row>>1)&3) = (tid&3) ^ ((tid>>3)&3).
    const int srow = tid >> 2;                // 0..127
    const int sgx = ((tid & 3) ^ ((tid >> 3) & 3)) * 8;
    const unsigned short* Ag = A + (size_t)(m0 + srow) * K + sgx;
    const unsigned short* Bg = B + (size_t)(n0 + srow) * K + sgx;
    const size_t j128K = (size_t)128 * K;

    f32x4 acc[MFR][4];
#pragma unroll
    for (int i = 0; i < MFR; i++)
#pragma unroll
        for (int j = 0; j < 4; j++) acc[i][j] = (f32x4){0.f, 0.f, 0.f, 0.f};

    const int NT = K >> 6;

    auto stage_half = [&](int t, int ks, int buf) {
        const size_t ko = (size_t)t * 64 + ks * 32;
#pragma unroll
        for (int j = 0; j < MFR / 4; j++)
            gload16(Ag + j * j128K + ko, As + buf * ABUF + ks * AHALF + j * 4096 + tid * 8);
#pragma unroll
        for (int j = 0; j < 2; j++)
            gload16(Bg + j * j128K + ko, Bs + buf * 16384 + ks * 8192 + j * 4096 + tid * 8);
    };

    // prologue: both halves of tile 0 -> buf 0; wait first half only
    stage_half(0, 0, 0);
    stage_half(0, 1, 0);
    vmwait<LPH>();
    __builtin_amdgcn_s_barrier();

    const int co = (lg ^ xr) * 8;
    const unsigned short* ArB = As + (size_t)(wm + lr) * 32 + co;
    const unsigned short* BrB = Bs + (size_t)(wn + lr) * 32 + co;

    for (int t = 0; t < NT; ++t) {
        const int b = t & 1;
        const bool notlast = (t + 1 < NT);
        const unsigned short* Ar0 = ArB + b * ABUF;            // ks0
        const unsigned short* Ar1 = Ar0 + AHALF;               // ks1
        const unsigned short* Br0 = BrB + b * 16384;
        const unsigned short* Br1 = Br0 + 8192;
        short8 af[MFR / 2], bf[4];

        // ---------- phase 0: ks0, M-half 0 (+ stage H(t+1,ks0)) ----------
        if (notlast) stage_half(t + 1, 0, b ^ 1);
#pragma unroll
        for (int ni = 0; ni < 4; ni++) bf[ni] = *(const short8*)(Br0 + ni * 512);
#pragma unroll
        for (int mi = 0; mi < MFR / 2; mi++) af[mi] = *(const short8*)(Ar0 + mi * 512);
        __builtin_amdgcn_s_barrier();
        asm volatile("s_waitcnt lgkmcnt(0)" ::: "memory");
        __builtin_amdgcn_sched_barrier(0);
        __builtin_amdgcn_s_setprio(1);
#pragma unroll
        for (int mi = 0; mi < MFR / 2; mi++)
#pragma unroll
            for (int ni = 0; ni < 4; ni++) mfma16(acc[mi][ni], af[mi], bf[ni]);
        __builtin_amdgcn_s_setprio(0);
        __builtin_amdgcn_s_barrier();

        // ---------- phase 1: ks0, M-half 1 (+ vmcnt completes H(t,ks1)) ----------
#pragma unroll
        for (int mi = 0; mi < MFR / 2; mi++)
            af[mi] = *(const short8*)(Ar0 + (MFR / 2 + mi) * 512);
        __builtin_amdgcn_s_barrier();
        asm volatile("s_waitcnt lgkmcnt(0)" ::: "memory");
        __builtin_amdgcn_sched_barrier(0);
        __builtin_amdgcn_s_setprio(1);
#pragma unroll
        for (int mi = 0; mi < MFR / 2; mi++)
#pragma unroll
            for (int ni = 0; ni < 4; ni++) mfma16(acc[MFR / 2 + mi][ni], af[mi], bf[ni]);
        __builtin_amdgcn_s_setprio(0);
        if (notlast) vmwait<LPH>(); else vmwait<0>();
        __builtin_amdgcn_s_barrier();

        // ---------- phase 2: ks1, M-half 0 (+ stage H(t+1,ks1)) ----------
        if (notlast) stage_half(t + 1, 1, b ^ 1);
#pragma unroll
        for (int ni = 0; ni < 4; ni++) bf[ni] = *(const short8*)(Br1 + ni * 512);
#pragma unroll
        for (int mi = 0; mi < MFR / 2; mi++) af[mi] = *(const short8*)(Ar1 + mi * 512);
        __builtin_amdgcn_s_barrier();
        asm volatile("s_waitcnt lgkmcnt(0)" ::: "memory");
        __builtin_amdgcn_sched_barrier(0);
        __builtin_amdgcn_s_setprio(1);
#pragma unroll
        for (int mi = 0; mi < MFR / 2; mi++)
#pragma unroll
            for (int ni = 0; ni < 4; ni++) mfma16(acc[mi][ni], af[mi], bf[ni]);
        __builtin_amdgcn_s_setprio(0);
        __builtin_amdgcn_s_barrier();

        // ---------- phase 3: ks1, M-half 1 (+ vmcnt completes H(t+1,ks0)) ----------
#pragma unroll
        for (int mi = 0; mi < MFR / 2; mi++)
            af[mi] = *(const short8*)(Ar1 + (MFR / 2 + mi) * 512);
        __builtin_amdgcn_s_barrier();
        asm volatile("s_waitcnt lgkmcnt(0)" ::: "memory");
        __builtin_amdgcn_sched_barrier(0);
        __builtin_amdgcn_s_setprio(1);
#pragma unroll
        for (int mi = 0; mi < MFR / 2; mi++)
#pragma unroll
            for (int ni = 0; ni < 4; ni++) mfma16(acc[MFR / 2 + mi][ni], af[mi], bf[ni]);
        __builtin_amdgcn_s_setprio(0);
        if (notlast) vmwait<LPH>();
        __builtin_amdgcn_s_barrier();
    }

    // ---------------- epilogue (unchanged from round 5) ----------------
#pragma unroll
    for (int ni = 0; ni < 4; ni++) {
        const int col = n0 + wn + ni * 16 + lr;
        const float bia = bias[col];
        const unsigned h = (unsigned)col / 192u;
        const int rem = col - (int)h * 192;
        const int tq = rem >> 6, d = rem & 63;
#pragma unroll
        for (int mi = 0; mi < MFR; mi++) {
            const int row = m0 + wm + mi * 16 + lg * 4;
            if (EPI == 1) {
#pragma unroll
                for (int r = 0; r < 4; r++)
                    Cf[(size_t)(row + r) * N + col] = acc[mi][ni][r] + bia;
            } else {
                const int bb = row >> 10, s = row & 1023;
                const int bh = bb * 16 + (int)h;
                if (tq == 0) {
#pragma unroll
                    for (int r = 0; r < 4; r++)
                        qb[((size_t)bh * 1024 + s + r) * 64 + d] =
                            f2bf((acc[mi][ni][r] + bia) * QSCALE);
                } else if (tq == 1) {
#pragma unroll
                    for (int r = 0; r < 4; r++)
                        kb[((size_t)bh * 1024 + s + r) * 64 + d] = f2bf(acc[mi][ni][r] + bia);
                } else {
                    uint2 pk;
                    pk.x = cvtpk(acc[mi][ni][0] + bia, acc[mi][ni][1] + bia);
                    pk.y = cvtpk(acc[mi][ni][2] + bia, acc[mi][ni][3] + bia);
                    *(uint2*)(vtb + ((size_t)bh * 64 + d) * 1024 + s) = pk;
                }
            }
        }
    }
}

// ---------------- flash attention (round-5 proven version, unchanged) ----------------
__device__ __forceinline__ void softmax_half(f32x4 (&s)[4], float& m, float& l,
                                             f32x4 (&o)[4], unsigned short* pbuf,
                                             int lr, int lg, int x7) {
    float mx = s[0][0];
#pragma unroll
    for (int kt = 0; kt < 4; kt++)
#pragma unroll
        for (int r = 0; r < 4; r++) mx = fmaxf(mx, s[kt][r]);
    mx = fmaxf(mx, __shfl_xor(mx, 16));
    mx = fmaxf(mx, __shfl_xor(mx, 32));
    const float mn = fmaxf(m, mx);
    const float alpha = __builtin_amdgcn_exp2f(m - mn);
    m = mn;
    float p[4][4];
    float rs = 0.f;
#pragma unroll
    for (int kt = 0; kt < 4; kt++)
#pragma unroll
        for (int r = 0; r < 4; r++) {
            p[kt][r] = __builtin_amdgcn_exp2f(s[kt][r] - mn);
            rs += p[kt][r];
        }
    rs += __shfl_xor(rs, 16);
    rs += __shfl_xor(rs, 32);
    l = l * alpha + rs;
#pragma unroll
    for (int mi = 0; mi < 4; mi++)
#pragma unroll
        for (int r = 0; r < 4; r++) o[mi][r] *= alpha;
#pragma unroll
    for (int kt = 0; kt < 4; kt++)
#pragma unroll
        for (int w2 = 0; w2 < 2; w2++) {
            const unsigned pk = cvtpk(p[kt][2 * w2], p[kt][2 * w2 + 1]);
            const int col = (kt * 16 + lg * 4 + 2 * w2) ^ (x7 << 3);
            *(unsigned*)(pbuf + lr * 64 + col) = pk;
        }
}

__global__ __launch_bounds__(256) void attn_fwd(
    const unsigned short* __restrict__ qg, const unsigned short* __restrict__ kg,
    const unsigned short* __restrict__ vtg, unsigned short* __restrict__ vals) {
    __shared__ unsigned short Ks[64 * 64];
    __shared__ unsigned short Vts[64 * 64];
    __shared__ unsigned short Ps[4 * 2048];
    const int tid = threadIdx.x, lane = tid & 63, w = tid >> 6;
    const int lr = lane & 15, lg = lane >> 4;
    const int x7 = lr & 7;
    const int bh = blockIdx.y;
    const int q0 = blockIdx.x * 128 + w * 32;

    const unsigned short* qrowA = qg + ((size_t)bh * 1024 + q0 + lr) * 64;
    const unsigned short* qrowB = qrowA + 16 * 64;
    short8 qA[2], qB[2];
    qA[0] = *(const short8*)(qrowA + lg * 8);
    qA[1] = *(const short8*)(qrowA + 32 + lg * 8);
    qB[0] = *(const short8*)(qrowB + lg * 8);
    qB[1] = *(const short8*)(qrowB + 32 + lg * 8);

    f32x4 oA[4], oB[4];
    float mA = -1e30f, mB = -1e30f, lA = 0.f, lB = 0.f;
#pragma unroll
    for (int i = 0; i < 4; i++) {
        oA[i] = (f32x4){0.f, 0.f, 0.f, 0.f};
        oB[i] = (f32x4){0.f, 0.f, 0.f, 0.f};
    }

    const unsigned short* kb = kg + (size_t)bh * 65536;
    const unsigned short* vb = vtg + (size_t)bh * 65536;
    unsigned short* pwl = Ps + w * 2048;

    const int srow = tid >> 3;
    const int scol = ((tid & 7) ^ (srow & 7)) * 8;

    for (int kv0 = 0; kv0 < 1024; kv0 += 64) {
        __syncthreads();
#pragma unroll
        for (int i = 0; i < 2; i++) {
            gload16(kb + (size_t)(kv0 + i * 32 + srow) * 64 + scol, Ks + i * 2048 + tid * 8);
            gload16(vb + (size_t)(i * 32 + srow) * 1024 + kv0 + scol, Vts + i * 2048 + tid * 8);
        }
        __syncthreads();

        f32x4 sA[4], sB[4];
#pragma unroll
        for (int i = 0; i < 4; i++) {
            sA[i] = (f32x4){0.f, 0.f, 0.f, 0.f};
            sB[i] = (f32x4){0.f, 0.f, 0.f, 0.f};
        }
#pragma unroll
        for (int kt = 0; kt < 4; kt++) {
            const short8 k0 = *(const short8*)(Ks + (kt * 16 + lr) * 64 + ((0 + lg) ^ x7) * 8);
            const short8 k1 = *(const short8*)(Ks + (kt * 16 + lr) * 64 + ((4 + lg) ^ x7) * 8);
            mfma16(sA[kt], k0, qA[0]);
            mfma16(sB[kt], k0, qB[0]);
            mfma16(sA[kt], k1, qA[1]);
            mfma16(sB[kt], k1, qB[1]);
        }

        softmax_half(sA, mA, lA, oA, pwl, lr, lg, x7);
        softmax_half(sB, mB, lB, oB, pwl + 1024, lr, lg, x7);

        short8 pA[2], pB[2];
#pragma unroll
        for (int ks2 = 0; ks2 < 2; ks2++) {
            pA[ks2] = *(const short8*)(pwl + lr * 64 + (((ks2 * 4 + lg) ^ x7) * 8));
            pB[ks2] = *(const short8*)(pwl + 1024 + lr * 64 + (((ks2 * 4 + lg) ^ x7) * 8));
        }
#pragma unroll
        for (int mi = 0; mi < 4; mi++) {
            const short8 v0 = *(const short8*)(Vts + (mi * 16 + lr) * 64 + ((0 + lg) ^ x7) * 8);
            const short8 v1 = *(const short8*)(Vts + (mi * 16 + lr) * 64 + ((4 + lg) ^ x7) * 8);
            mfma16(oA[mi], v0, pA[0]);
            mfma16(oB[mi], v0, pB[0]);
            mfma16(oA[mi], v1, pA[1]);
            mfma16(oB[mi], v1, pB[1]);
        }
    }

    const int bb = bh >> 4, hh = bh & 15;
    {
        const float inv = 1.f / lA;
        unsigned short* vp = vals + (size_t)(bb * 1024 + q0 + lr) * 1024 + hh * 64 + lg * 4;
#pragma unroll
        for (int mi = 0; mi < 4; mi++) {
            uint2 st;
            st.x = cvtpk(oA[mi][0] * inv, oA[mi][1] * inv);
            st.y = cvtpk(oA[mi][2] * inv, oA[mi][3] * inv);
            *(uint2*)(vp + mi * 16) = st;
        }
    }
    {
        const float inv = 1.f / lB;
        unsigned short* vp = vals + (size_t)(bb * 1024 + q0 + 16 + lr) * 1024 + hh * 64 + lg * 4;
#pragma unroll
        for (int mi = 0; mi < 4; mi++) {
            uint2 st;
            st.x = cvtpk(oB[mi][0] * inv, oB[mi][1] * inv);
            st.y = cvtpk(oB[mi][2] * inv, oB[mi][3] * inv);
            *(uint2*)(vp + mi * 16) = st;
        }
    }
}

extern "C" void kernel_launch(void* const* d_in, const int* in_sizes, int n_in,
                              void* d_out, int out_size, void* d_ws, size_t ws_size,
                              hipStream_t stream) {
    const float* x = (const float*)d_in[0];
    const float* w_in = (const float*)d_in[1];
    const float* b_in = (const float*)d_in[2];
    const float* w_out = (const float*)d_in[3];
    const float* b_out = (const float*)d_in[4];
    float* out = (float*)d_out;

    unsigned short* ws = (unsigned short*)d_ws;
    unsigned short* xb = ws;                   // 8388608  (reused as vals)
    unsigned short* winb = xb + 8388608;       // 3145728
    unsigned short* woutb = winb + 3145728;    // 1048576
    unsigned short* qb = woutb + 1048576;      // 8388608  (Q [bh,1024,64], pre-scaled)
    unsigned short* kb = qb + 8388608;         // 8388608
    unsigned short* vtb = kb + 8388608;        // 8388608  (V^T [bh,64,1024])
    unsigned short* vals = xb;                 // alias

    hipFuncSetAttribute((const void*)gemm256<0, 8>,
                        hipFuncAttributeMaxDynamicSharedMemorySize, 131072);
    hipFuncSetAttribute((const void*)gemm256<1, 4>,
                        hipFuncAttributeMaxDynamicSharedMemorySize, 98304);

    cvt_f32_bf16<<<2048, 256, 0, stream>>>(x, xb, 8388608 / 4);
    cvt_f32_bf16<<<1024, 256, 0, stream>>>(w_in, winb, 3145728 / 4);
    cvt_f32_bf16<<<512, 256, 0, stream>>>(w_out, woutb, 1048576 / 4);

    // QKV: BM=256 -> grid 32x12 = 384; proj: BM=128 -> grid 64x4 = 256
    gemm256<0, 8><<<384, 512, 131072, stream>>>(xb, winb, b_in, 1024, 12, 3072,
                                                nullptr, qb, kb, vtb);
    attn_fwd<<<dim3(8, 128), 256, 0, stream>>>(qb, kb, vtb, vals);
    gemm256<1, 4><<<256, 512, 98304, stream>>>(vals, woutb, b_out, 1024, 4, 1024,
                                               out, nullptr, nullptr, nullptr);
}

// Round 7
// 161.591 us; speedup vs baseline: 1.1523x; 1.1523x over previous
//
#include <hip/hip_runtime.h>

typedef short short8 __attribute__((ext_vector_type(8)));
typedef float f32x4 __attribute__((ext_vector_type(4)));

#define AS1 __attribute__((address_space(1)))
#define AS3 __attribute__((address_space(3)))

__device__ __forceinline__ void gload16(const void* g, void* l) {
    __builtin_amdgcn_global_load_lds((const AS1 unsigned int*)g, (AS3 unsigned int*)l, 16, 0, 0);
}

__device__ __forceinline__ unsigned short f2bf(float f) {
    union { float f; unsigned u; } c; c.f = f;
    unsigned r = (c.u + 0x7FFFu + ((c.u >> 16) & 1u)) >> 16;
    return (unsigned short)r;
}

__device__ __forceinline__ unsigned cvtpk(float a, float b) {
    unsigned r;
    asm("v_cvt_pk_bf16_f32 %0, %1, %2" : "=v"(r) : "v"(a), "v"(b));
    return r;
}

__device__ __forceinline__ void mfma16(f32x4& d, short8 a, short8 b) {
    asm("v_mfma_f32_16x16x32_bf16 %0, %1, %2, %0" : "+v"(d) : "v"(a), "v"(b));
}

// q pre-scale: 1/sqrt(64) * log2(e) -> softmax via exp2
#define QSCALE 0.18033688011112042f

// ---------------- fp32 -> bf16 convert ----------------
__global__ __launch_bounds__(256) void cvt_f32_bf16(const float* __restrict__ in,
                                                    unsigned short* __restrict__ out, int n4) {
    int idx = blockIdx.x * 256 + threadIdx.x;
    int stride = gridDim.x * 256;
    for (int i = idx; i < n4; i += stride) {
        float4 v = ((const float4*)in)[i];
        ushort4 o;
        o.x = f2bf(v.x); o.y = f2bf(v.y); o.z = f2bf(v.z); o.w = f2bf(v.w);
        ((ushort4*)out)[i] = o;
    }
}

// ---------------- 128x128 NT GEMM (round-2 structure + XOR swizzle) ----------------
// C[M,N] = A[M,K] * B[N,K]^T + bias. 256 thr = 4 waves (2M x 2N), 64x64 per wave.
// LDS: As[128][64], Bs[128][64] bf16, single-buffered (32 KB -> multi-block TLP).
// Swizzle: 16B-chunk c' = c ^ (row&7), both sides (pre-swizzled global source col;
// read applies same XOR). Fragment reads: 2-way bank aliasing = free (m136).
template <int EPI>
__global__ __launch_bounds__(256) void gemm_nt(
    const unsigned short* __restrict__ A, const unsigned short* __restrict__ B,
    const float* __restrict__ bias, int M, int N, int K,
    float* __restrict__ Cf, unsigned short* __restrict__ qb,
    unsigned short* __restrict__ kb, unsigned short* __restrict__ vtb) {
    __shared__ unsigned short As[128 * 64];
    __shared__ unsigned short Bs[128 * 64];
    const int tid = threadIdx.x;
    const int lane = tid & 63;
    const int wv = tid >> 6;
    const int wm = (wv >> 1) * 64, wn = (wv & 1) * 64;
    const int lr = lane & 15, lg = lane >> 4;
    const int x7 = lr & 7;
    const int m0 = blockIdx.x * 128, n0 = blockIdx.y * 128;

    f32x4 acc[4][4];
#pragma unroll
    for (int i = 0; i < 4; i++)
#pragma unroll
        for (int j = 0; j < 4; j++) acc[i][j] = (f32x4){0.f, 0.f, 0.f, 0.f};

    // staging: thread -> linear LDS slot (row = i*32 + tid>>3, chunk = tid&7);
    // global source chunk pre-swizzled: (tid&7) ^ (row&7), row&7 = (tid>>3)&7.
    const int sr = tid >> 3;
    const int sc = ((tid & 7) ^ ((tid >> 3) & 7)) * 8;
    const unsigned short* Ag = A + (size_t)(m0 + sr) * K + sc;
    const unsigned short* Bg = B + (size_t)(n0 + sr) * K + sc;
    unsigned short* Asl = As + tid * 8;
    unsigned short* Bsl = Bs + tid * 8;

    for (int kt = 0; kt < K; kt += 64) {
        __syncthreads();
#pragma unroll
        for (int i = 0; i < 4; i++) {
            gload16(Ag + (size_t)(i * 32) * K + kt, Asl + i * 2048);
            gload16(Bg + (size_t)(i * 32) * K + kt, Bsl + i * 2048);
        }
        __syncthreads();
#pragma unroll
        for (int ks = 0; ks < 2; ks++) {
            short8 af[4], bf[4];
#pragma unroll
            for (int mi = 0; mi < 4; mi++)
                af[mi] = *(const short8*)(As + (wm + mi * 16 + lr) * 64 +
                                          (((ks * 4 + lg) ^ x7) * 8));
#pragma unroll
            for (int ni = 0; ni < 4; ni++)
                bf[ni] = *(const short8*)(Bs + (wn + ni * 16 + lr) * 64 +
                                          (((ks * 4 + lg) ^ x7) * 8));
#pragma unroll
            for (int mi = 0; mi < 4; mi++)
#pragma unroll
                for (int ni = 0; ni < 4; ni++) mfma16(acc[mi][ni], af[mi], bf[ni]);
        }
    }

    // ---------------- epilogue ----------------
#pragma unroll
    for (int ni = 0; ni < 4; ni++) {
        const int col = n0 + wn + ni * 16 + lr;
        const float bia = bias[col];
        const unsigned h = (unsigned)col / 192u;
        const int rem = col - (int)h * 192;
        const int tq = rem >> 6, d = rem & 63;
#pragma unroll
        for (int mi = 0; mi < 4; mi++) {
            const int row = m0 + wm + mi * 16 + lg * 4;
            if (EPI == 1) {
#pragma unroll
                for (int r = 0; r < 4; r++)
                    Cf[(size_t)(row + r) * N + col] = acc[mi][ni][r] + bia;
            } else {
                const int bb = row >> 10, s = row & 1023;
                const int bh = bb * 16 + (int)h;
                if (tq == 0) {
#pragma unroll
                    for (int r = 0; r < 4; r++)
                        qb[((size_t)bh * 1024 + s + r) * 64 + d] =
                            f2bf((acc[mi][ni][r] + bia) * QSCALE);
                } else if (tq == 1) {
#pragma unroll
                    for (int r = 0; r < 4; r++)
                        kb[((size_t)bh * 1024 + s + r) * 64 + d] = f2bf(acc[mi][ni][r] + bia);
                } else {
                    uint2 pk;
                    pk.x = cvtpk(acc[mi][ni][0] + bia, acc[mi][ni][1] + bia);
                    pk.y = cvtpk(acc[mi][ni][2] + bia, acc[mi][ni][3] + bia);
                    *(uint2*)(vtb + ((size_t)bh * 64 + d) * 1024 + s) = pk;
                }
            }
        }
    }
}

// ---------------- flash attention (round-5 proven version, unchanged) ----------------
__device__ __forceinline__ void softmax_half(f32x4 (&s)[4], float& m, float& l,
                                             f32x4 (&o)[4], unsigned short* pbuf,
                                             int lr, int lg, int x7) {
    float mx = s[0][0];
#pragma unroll
    for (int kt = 0; kt < 4; kt++)
#pragma unroll
        for (int r = 0; r < 4; r++) mx = fmaxf(mx, s[kt][r]);
    mx = fmaxf(mx, __shfl_xor(mx, 16));
    mx = fmaxf(mx, __shfl_xor(mx, 32));
    const float mn = fmaxf(m, mx);
    const float alpha = __builtin_amdgcn_exp2f(m - mn);
    m = mn;
    float p[4][4];
    float rs = 0.f;
#pragma unroll
    for (int kt = 0; kt < 4; kt++)
#pragma unroll
        for (int r = 0; r < 4; r++) {
            p[kt][r] = __builtin_amdgcn_exp2f(s[kt][r] - mn);
            rs += p[kt][r];
        }
    rs += __shfl_xor(rs, 16);
    rs += __shfl_xor(rs, 32);
    l = l * alpha + rs;
#pragma unroll
    for (int mi = 0; mi < 4; mi++)
#pragma unroll
        for (int r = 0; r < 4; r++) o[mi][r] *= alpha;
#pragma unroll
    for (int kt = 0; kt < 4; kt++)
#pragma unroll
        for (int w2 = 0; w2 < 2; w2++) {
            const unsigned pk = cvtpk(p[kt][2 * w2], p[kt][2 * w2 + 1]);
            const int col = (kt * 16 + lg * 4 + 2 * w2) ^ (x7 << 3);
            *(unsigned*)(pbuf + lr * 64 + col) = pk;
        }
}

__global__ __launch_bounds__(256) void attn_fwd(
    const unsigned short* __restrict__ qg, const unsigned short* __restrict__ kg,
    const unsigned short* __restrict__ vtg, unsigned short* __restrict__ vals) {
    __shared__ unsigned short Ks[64 * 64];
    __shared__ unsigned short Vts[64 * 64];
    __shared__ unsigned short Ps[4 * 2048];
    const int tid = threadIdx.x, lane = tid & 63, w = tid >> 6;
    const int lr = lane & 15, lg = lane >> 4;
    const int x7 = lr & 7;
    const int bh = blockIdx.y;
    const int q0 = blockIdx.x * 128 + w * 32;

    const unsigned short* qrowA = qg + ((size_t)bh * 1024 + q0 + lr) * 64;
    const unsigned short* qrowB = qrowA + 16 * 64;
    short8 qA[2], qB[2];
    qA[0] = *(const short8*)(qrowA + lg * 8);
    qA[1] = *(const short8*)(qrowA + 32 + lg * 8);
    qB[0] = *(const short8*)(qrowB + lg * 8);
    qB[1] = *(const short8*)(qrowB + 32 + lg * 8);

    f32x4 oA[4], oB[4];
    float mA = -1e30f, mB = -1e30f, lA = 0.f, lB = 0.f;
#pragma unroll
    for (int i = 0; i < 4; i++) {
        oA[i] = (f32x4){0.f, 0.f, 0.f, 0.f};
        oB[i] = (f32x4){0.f, 0.f, 0.f, 0.f};
    }

    const unsigned short* kb = kg + (size_t)bh * 65536;
    const unsigned short* vb = vtg + (size_t)bh * 65536;
    unsigned short* pwl = Ps + w * 2048;

    const int srow = tid >> 3;
    const int scol = ((tid & 7) ^ (srow & 7)) * 8;

    for (int kv0 = 0; kv0 < 1024; kv0 += 64) {
        __syncthreads();
#pragma unroll
        for (int i = 0; i < 2; i++) {
            gload16(kb + (size_t)(kv0 + i * 32 + srow) * 64 + scol, Ks + i * 2048 + tid * 8);
            gload16(vb + (size_t)(i * 32 + srow) * 1024 + kv0 + scol, Vts + i * 2048 + tid * 8);
        }
        __syncthreads();

        f32x4 sA[4], sB[4];
#pragma unroll
        for (int i = 0; i < 4; i++) {
            sA[i] = (f32x4){0.f, 0.f, 0.f, 0.f};
            sB[i] = (f32x4){0.f, 0.f, 0.f, 0.f};
        }
#pragma unroll
        for (int kt = 0; kt < 4; kt++) {
            const short8 k0 = *(const short8*)(Ks + (kt * 16 + lr) * 64 + ((0 + lg) ^ x7) * 8);
            const short8 k1 = *(const short8*)(Ks + (kt * 16 + lr) * 64 + ((4 + lg) ^ x7) * 8);
            mfma16(sA[kt], k0, qA[0]);
            mfma16(sB[kt], k0, qB[0]);
            mfma16(sA[kt], k1, qA[1]);
            mfma16(sB[kt], k1, qB[1]);
        }

        softmax_half(sA, mA, lA, oA, pwl, lr, lg, x7);
        softmax_half(sB, mB, lB, oB, pwl + 1024, lr, lg, x7);

        short8 pA[2], pB[2];
#pragma unroll
        for (int ks2 = 0; ks2 < 2; ks2++) {
            pA[ks2] = *(const short8*)(pwl + lr * 64 + (((ks2 * 4 + lg) ^ x7) * 8));
            pB[ks2] = *(const short8*)(pwl + 1024 + lr * 64 + (((ks2 * 4 + lg) ^ x7) * 8));
        }
#pragma unroll
        for (int mi = 0; mi < 4; mi++) {
            const short8 v0 = *(const short8*)(Vts + (mi * 16 + lr) * 64 + ((0 + lg) ^ x7) * 8);
            const short8 v1 = *(const short8*)(Vts + (mi * 16 + lr) * 64 + ((4 + lg) ^ x7) * 8);
            mfma16(oA[mi], v0, pA[0]);
            mfma16(oB[mi], v0, pB[0]);
            mfma16(oA[mi], v1, pA[1]);
            mfma16(oB[mi], v1, pB[1]);
        }
    }

    const int bb = bh >> 4, hh = bh & 15;
    {
        const float inv = 1.f / lA;
        unsigned short* vp = vals + (size_t)(bb * 1024 + q0 + lr) * 1024 + hh * 64 + lg * 4;
#pragma unroll
        for (int mi = 0; mi < 4; mi++) {
            uint2 st;
            st.x = cvtpk(oA[mi][0] * inv, oA[mi][1] * inv);
            st.y = cvtpk(oA[mi][2] * inv, oA[mi][3] * inv);
            *(uint2*)(vp + mi * 16) = st;
        }
    }
    {
        const float inv = 1.f / lB;
        unsigned short* vp = vals + (size_t)(bb * 1024 + q0 + 16 + lr) * 1024 + hh * 64 + lg * 4;
#pragma unroll
        for (int mi = 0; mi < 4; mi++) {
            uint2 st;
            st.x = cvtpk(oB[mi][0] * inv, oB[mi][1] * inv);
            st.y = cvtpk(oB[mi][2] * inv, oB[mi][3] * inv);
            *(uint2*)(vp + mi * 16) = st;
        }
    }
}

extern "C" void kernel_launch(void* const* d_in, const int* in_sizes, int n_in,
                              void* d_out, int out_size, void* d_ws, size_t ws_size,
                              hipStream_t stream) {
    const float* x = (const float*)d_in[0];
    const float* w_in = (const float*)d_in[1];
    const float* b_in = (const float*)d_in[2];
    const float* w_out = (const float*)d_in[3];
    const float* b_out = (const float*)d_in[4];
    float* out = (float*)d_out;

    unsigned short* ws = (unsigned short*)d_ws;
    unsigned short* xb = ws;                   // 8388608  (reused as vals)
    unsigned short* winb = xb + 8388608;       // 3145728
    unsigned short* woutb = winb + 3145728;    // 1048576
    unsigned short* qb = woutb + 1048576;      // 8388608  (Q [bh,1024,64], pre-scaled)
    unsigned short* kb = qb + 8388608;         // 8388608
    unsigned short* vtb = kb + 8388608;        // 8388608  (V^T [bh,64,1024])
    unsigned short* vals = xb;                 // alias

    cvt_f32_bf16<<<2048, 256, 0, stream>>>(x, xb, 8388608 / 4);
    cvt_f32_bf16<<<1024, 256, 0, stream>>>(w_in, winb, 3145728 / 4);
    cvt_f32_bf16<<<512, 256, 0, stream>>>(w_out, woutb, 1048576 / 4);

    gemm_nt<0><<<dim3(64, 24), 256, 0, stream>>>(xb, winb, b_in, 8192, 3072, 1024,
                                                 nullptr, qb, kb, vtb);
    attn_fwd<<<dim3(8, 128), 256, 0, stream>>>(qb, kb, vtb, vals);
    gemm_nt<1><<<dim3(64, 8), 256, 0, stream>>>(vals, woutb, b_out, 8192, 1024, 1024,
                                                out, nullptr, nullptr, nullptr);
}

// Round 8
// 157.621 us; speedup vs baseline: 1.1813x; 1.0252x over previous
//
#include <hip/hip_runtime.h>

typedef short short8 __attribute__((ext_vector_type(8)));
typedef float f32x4 __attribute__((ext_vector_type(4)));

#define AS1 __attribute__((address_space(1)))
#define AS3 __attribute__((address_space(3)))

__device__ __forceinline__ void gload16(const void* g, void* l) {
    __builtin_amdgcn_global_load_lds((const AS1 unsigned int*)g, (AS3 unsigned int*)l, 16, 0, 0);
}

__device__ __forceinline__ unsigned short f2bf(float f) {
    union { float f; unsigned u; } c; c.f = f;
    unsigned r = (c.u + 0x7FFFu + ((c.u >> 16) & 1u)) >> 16;
    return (unsigned short)r;
}

__device__ __forceinline__ unsigned cvtpk(float a, float b) {
    unsigned r;
    asm("v_cvt_pk_bf16_f32 %0, %1, %2" : "=v"(r) : "v"(a), "v"(b));
    return r;
}

__device__ __forceinline__ void mfma16(f32x4& d, short8 a, short8 b) {
    asm("v_mfma_f32_16x16x32_bf16 %0, %1, %2, %0" : "+v"(d) : "v"(a), "v"(b));
}

// q pre-scale: 1/sqrt(64) * log2(e) -> softmax via exp2
#define QSCALE 0.18033688011112042f

// ---------------- fused fp32 -> bf16 convert (x, w_in, w_out in one launch) ----------------
#define XN4 2097152
#define WIN4 786432
#define WOUT4 262144
__global__ __launch_bounds__(256) void cvt_all(const float* __restrict__ x,
                                               const float* __restrict__ w_in,
                                               const float* __restrict__ w_out,
                                               unsigned short* __restrict__ xb,
                                               unsigned short* __restrict__ winb,
                                               unsigned short* __restrict__ woutb) {
    int idx = blockIdx.x * 256 + threadIdx.x;
    int stride = gridDim.x * 256;
    for (int i = idx; i < XN4 + WIN4 + WOUT4; i += stride) {
        const float4* src;
        ushort4* dst;
        int j;
        if (i < XN4) {
            src = (const float4*)x; dst = (ushort4*)xb; j = i;
        } else if (i < XN4 + WIN4) {
            src = (const float4*)w_in; dst = (ushort4*)winb; j = i - XN4;
        } else {
            src = (const float4*)w_out; dst = (ushort4*)woutb; j = i - XN4 - WIN4;
        }
        float4 v = src[j];
        ushort4 o;
        o.x = f2bf(v.x); o.y = f2bf(v.y); o.z = f2bf(v.z); o.w = f2bf(v.w);
        dst[j] = o;
    }
}

// ---------------- 128x128 NT GEMM (round-7 proven, unchanged) ----------------
template <int EPI>
__global__ __launch_bounds__(256) void gemm_nt(
    const unsigned short* __restrict__ A, const unsigned short* __restrict__ B,
    const float* __restrict__ bias, int M, int N, int K,
    float* __restrict__ Cf, unsigned short* __restrict__ qb,
    unsigned short* __restrict__ kb, unsigned short* __restrict__ vtb) {
    __shared__ unsigned short As[128 * 64];
    __shared__ unsigned short Bs[128 * 64];
    const int tid = threadIdx.x;
    const int lane = tid & 63;
    const int wv = tid >> 6;
    const int wm = (wv >> 1) * 64, wn = (wv & 1) * 64;
    const int lr = lane & 15, lg = lane >> 4;
    const int x7 = lr & 7;
    const int m0 = blockIdx.x * 128, n0 = blockIdx.y * 128;

    f32x4 acc[4][4];
#pragma unroll
    for (int i = 0; i < 4; i++)
#pragma unroll
        for (int j = 0; j < 4; j++) acc[i][j] = (f32x4){0.f, 0.f, 0.f, 0.f};

    const int sr = tid >> 3;
    const int sc = ((tid & 7) ^ ((tid >> 3) & 7)) * 8;
    const unsigned short* Ag = A + (size_t)(m0 + sr) * K + sc;
    const unsigned short* Bg = B + (size_t)(n0 + sr) * K + sc;
    unsigned short* Asl = As + tid * 8;
    unsigned short* Bsl = Bs + tid * 8;

    for (int kt = 0; kt < K; kt += 64) {
        __syncthreads();
#pragma unroll
        for (int i = 0; i < 4; i++) {
            gload16(Ag + (size_t)(i * 32) * K + kt, Asl + i * 2048);
            gload16(Bg + (size_t)(i * 32) * K + kt, Bsl + i * 2048);
        }
        __syncthreads();
#pragma unroll
        for (int ks = 0; ks < 2; ks++) {
            short8 af[4], bf[4];
#pragma unroll
            for (int mi = 0; mi < 4; mi++)
                af[mi] = *(const short8*)(As + (wm + mi * 16 + lr) * 64 +
                                          (((ks * 4 + lg) ^ x7) * 8));
#pragma unroll
            for (int ni = 0; ni < 4; ni++)
                bf[ni] = *(const short8*)(Bs + (wn + ni * 16 + lr) * 64 +
                                          (((ks * 4 + lg) ^ x7) * 8));
            __builtin_amdgcn_s_setprio(1);
#pragma unroll
            for (int mi = 0; mi < 4; mi++)
#pragma unroll
                for (int ni = 0; ni < 4; ni++) mfma16(acc[mi][ni], af[mi], bf[ni]);
            __builtin_amdgcn_s_setprio(0);
        }
    }

    // ---------------- epilogue ----------------
#pragma unroll
    for (int ni = 0; ni < 4; ni++) {
        const int col = n0 + wn + ni * 16 + lr;
        const float bia = bias[col];
        const unsigned h = (unsigned)col / 192u;
        const int rem = col - (int)h * 192;
        const int tq = rem >> 6, d = rem & 63;
#pragma unroll
        for (int mi = 0; mi < 4; mi++) {
            const int row = m0 + wm + mi * 16 + lg * 4;
            if (EPI == 1) {
#pragma unroll
                for (int r = 0; r < 4; r++)
                    Cf[(size_t)(row + r) * N + col] = acc[mi][ni][r] + bia;
            } else {
                const int bb = row >> 10, s = row & 1023;
                const int bh = bb * 16 + (int)h;
                if (tq == 0) {
#pragma unroll
                    for (int r = 0; r < 4; r++)
                        qb[((size_t)bh * 1024 + s + r) * 64 + d] =
                            f2bf((acc[mi][ni][r] + bia) * QSCALE);
                } else if (tq == 1) {
#pragma unroll
                    for (int r = 0; r < 4; r++)
                        kb[((size_t)bh * 1024 + s + r) * 64 + d] = f2bf(acc[mi][ni][r] + bia);
                } else {
                    uint2 pk;
                    pk.x = cvtpk(acc[mi][ni][0] + bia, acc[mi][ni][1] + bia);
                    pk.y = cvtpk(acc[mi][ni][2] + bia, acc[mi][ni][3] + bia);
                    *(uint2*)(vtb + ((size_t)bh * 64 + d) * 1024 + s) = pk;
                }
            }
        }
    }
}

// ---------------- flash attention (round-7 proven + XCD-local KV grid + setprio) ----------------
__device__ __forceinline__ void softmax_half(f32x4 (&s)[4], float& m, float& l,
                                             f32x4 (&o)[4], unsigned short* pbuf,
                                             int lr, int lg, int x7) {
    float mx = s[0][0];
#pragma unroll
    for (int kt = 0; kt < 4; kt++)
#pragma unroll
        for (int r = 0; r < 4; r++) mx = fmaxf(mx, s[kt][r]);
    mx = fmaxf(mx, __shfl_xor(mx, 16));
    mx = fmaxf(mx, __shfl_xor(mx, 32));
    const float mn = fmaxf(m, mx);
    const float alpha = __builtin_amdgcn_exp2f(m - mn);
    m = mn;
    float p[4][4];
    float rs = 0.f;
#pragma unroll
    for (int kt = 0; kt < 4; kt++)
#pragma unroll
        for (int r = 0; r < 4; r++) {
            p[kt][r] = __builtin_amdgcn_exp2f(s[kt][r] - mn);
            rs += p[kt][r];
        }
    rs += __shfl_xor(rs, 16);
    rs += __shfl_xor(rs, 32);
    l = l * alpha + rs;
#pragma unroll
    for (int mi = 0; mi < 4; mi++)
#pragma unroll
        for (int r = 0; r < 4; r++) o[mi][r] *= alpha;
#pragma unroll
    for (int kt = 0; kt < 4; kt++)
#pragma unroll
        for (int w2 = 0; w2 < 2; w2++) {
            const unsigned pk = cvtpk(p[kt][2 * w2], p[kt][2 * w2 + 1]);
            const int col = (kt * 16 + lg * 4 + 2 * w2) ^ (x7 << 3);
            *(unsigned*)(pbuf + lr * 64 + col) = pk;
        }
}

__global__ __launch_bounds__(256) void attn_fwd(
    const unsigned short* __restrict__ qg, const unsigned short* __restrict__ kg,
    const unsigned short* __restrict__ vtg, unsigned short* __restrict__ vals) {
    __shared__ unsigned short Ks[64 * 64];
    __shared__ unsigned short Vts[64 * 64];
    __shared__ unsigned short Ps[4 * 2048];
    const int tid = threadIdx.x, lane = tid & 63, w = tid >> 6;
    const int lr = lane & 15, lg = lane >> 4;
    const int x7 = lr & 7;
    // grid = (128 bh, 8 qblk): linear bid = qblk*128 + bh -> bid%8 = bh%8, so all
    // 8 q-blocks sharing one bh's K/V land on the same XCD (KV served from its L2).
    const int bh = blockIdx.x;
    const int q0 = blockIdx.y * 128 + w * 32;

    const unsigned short* qrowA = qg + ((size_t)bh * 1024 + q0 + lr) * 64;
    const unsigned short* qrowB = qrowA + 16 * 64;
    short8 qA[2], qB[2];
    qA[0] = *(const short8*)(qrowA + lg * 8);
    qA[1] = *(const short8*)(qrowA + 32 + lg * 8);
    qB[0] = *(const short8*)(qrowB + lg * 8);
    qB[1] = *(const short8*)(qrowB + 32 + lg * 8);

    f32x4 oA[4], oB[4];
    float mA = -1e30f, mB = -1e30f, lA = 0.f, lB = 0.f;
#pragma unroll
    for (int i = 0; i < 4; i++) {
        oA[i] = (f32x4){0.f, 0.f, 0.f, 0.f};
        oB[i] = (f32x4){0.f, 0.f, 0.f, 0.f};
    }

    const unsigned short* kb = kg + (size_t)bh * 65536;
    const unsigned short* vb = vtg + (size_t)bh * 65536;
    unsigned short* pwl = Ps + w * 2048;

    const int srow = tid >> 3;
    const int scol = ((tid & 7) ^ (srow & 7)) * 8;

    for (int kv0 = 0; kv0 < 1024; kv0 += 64) {
        __syncthreads();
#pragma unroll
        for (int i = 0; i < 2; i++) {
            gload16(kb + (size_t)(kv0 + i * 32 + srow) * 64 + scol, Ks + i * 2048 + tid * 8);
            gload16(vb + (size_t)(i * 32 + srow) * 1024 + kv0 + scol, Vts + i * 2048 + tid * 8);
        }
        __syncthreads();

        f32x4 sA[4], sB[4];
#pragma unroll
        for (int i = 0; i < 4; i++) {
            sA[i] = (f32x4){0.f, 0.f, 0.f, 0.f};
            sB[i] = (f32x4){0.f, 0.f, 0.f, 0.f};
        }
#pragma unroll
        for (int kt = 0; kt < 4; kt++) {
            const short8 k0 = *(const short8*)(Ks + (kt * 16 + lr) * 64 + ((0 + lg) ^ x7) * 8);
            const short8 k1 = *(const short8*)(Ks + (kt * 16 + lr) * 64 + ((4 + lg) ^ x7) * 8);
            __builtin_amdgcn_s_setprio(1);
            mfma16(sA[kt], k0, qA[0]);
            mfma16(sB[kt], k0, qB[0]);
            mfma16(sA[kt], k1, qA[1]);
            mfma16(sB[kt], k1, qB[1]);
            __builtin_amdgcn_s_setprio(0);
        }

        softmax_half(sA, mA, lA, oA, pwl, lr, lg, x7);
        softmax_half(sB, mB, lB, oB, pwl + 1024, lr, lg, x7);

        short8 pA[2], pB[2];
#pragma unroll
        for (int ks2 = 0; ks2 < 2; ks2++) {
            pA[ks2] = *(const short8*)(pwl + lr * 64 + (((ks2 * 4 + lg) ^ x7) * 8));
            pB[ks2] = *(const short8*)(pwl + 1024 + lr * 64 + (((ks2 * 4 + lg) ^ x7) * 8));
        }
#pragma unroll
        for (int mi = 0; mi < 4; mi++) {
            const short8 v0 = *(const short8*)(Vts + (mi * 16 + lr) * 64 + ((0 + lg) ^ x7) * 8);
            const short8 v1 = *(const short8*)(Vts + (mi * 16 + lr) * 64 + ((4 + lg) ^ x7) * 8);
            __builtin_amdgcn_s_setprio(1);
            mfma16(oA[mi], v0, pA[0]);
            mfma16(oB[mi], v0, pB[0]);
            mfma16(oA[mi], v1, pA[1]);
            mfma16(oB[mi], v1, pB[1]);
            __builtin_amdgcn_s_setprio(0);
        }
    }

    const int bb = bh >> 4, hh = bh & 15;
    {
        const float inv = 1.f / lA;
        unsigned short* vp = vals + (size_t)(bb * 1024 + q0 + lr) * 1024 + hh * 64 + lg * 4;
#pragma unroll
        for (int mi = 0; mi < 4; mi++) {
            uint2 st;
            st.x = cvtpk(oA[mi][0] * inv, oA[mi][1] * inv);
            st.y = cvtpk(oA[mi][2] * inv, oA[mi][3] * inv);
            *(uint2*)(vp + mi * 16) = st;
        }
    }
    {
        const float inv = 1.f / lB;
        unsigned short* vp = vals + (size_t)(bb * 1024 + q0 + 16 + lr) * 1024 + hh * 64 + lg * 4;
#pragma unroll
        for (int mi = 0; mi < 4; mi++) {
            uint2 st;
            st.x = cvtpk(oB[mi][0] * inv, oB[mi][1] * inv);
            st.y = cvtpk(oB[mi][2] * inv, oB[mi][3] * inv);
            *(uint2*)(vp + mi * 16) = st;
        }
    }
}

extern "C" void kernel_launch(void* const* d_in, const int* in_sizes, int n_in,
                              void* d_out, int out_size, void* d_ws, size_t ws_size,
                              hipStream_t stream) {
    const float* x = (const float*)d_in[0];
    const float* w_in = (const float*)d_in[1];
    const float* b_in = (const float*)d_in[2];
    const float* w_out = (const float*)d_in[3];
    const float* b_out = (const float*)d_in[4];
    float* out = (float*)d_out;

    unsigned short* ws = (unsigned short*)d_ws;
    unsigned short* xb = ws;                   // 8388608  (reused as vals)
    unsigned short* winb = xb + 8388608;       // 3145728
    unsigned short* woutb = winb + 3145728;    // 1048576
    unsigned short* qb = woutb + 1048576;      // 8388608  (Q [bh,1024,64], pre-scaled)
    unsigned short* kb = qb + 8388608;         // 8388608
    unsigned short* vtb = kb + 8388608;        // 8388608  (V^T [bh,64,1024])
    unsigned short* vals = xb;                 // alias

    cvt_all<<<2048, 256, 0, stream>>>(x, w_in, w_out, xb, winb, woutb);

    gemm_nt<0><<<dim3(64, 24), 256, 0, stream>>>(xb, winb, b_in, 8192, 3072, 1024,
                                                 nullptr, qb, kb, vtb);
    attn_fwd<<<dim3(128, 8), 256, 0, stream>>>(qb, kb, vtb, vals);
    gemm_nt<1><<<dim3(64, 8), 256, 0, stream>>>(vals, woutb, b_out, 8192, 1024, 1024,
                                                out, nullptr, nullptr, nullptr);
}

// Round 9
// 154.118 us; speedup vs baseline: 1.2082x; 1.0227x over previous
//
#include <hip/hip_runtime.h>

typedef short short8 __attribute__((ext_vector_type(8)));
typedef float f32x4 __attribute__((ext_vector_type(4)));

#define AS1 __attribute__((address_space(1)))
#define AS3 __attribute__((address_space(3)))

__device__ __forceinline__ void gload16(const void* g, void* l) {
    __builtin_amdgcn_global_load_lds((const AS1 unsigned int*)g, (AS3 unsigned int*)l, 16, 0, 0);
}

__device__ __forceinline__ unsigned short f2bf(float f) {
    union { float f; unsigned u; } c; c.f = f;
    unsigned r = (c.u + 0x7FFFu + ((c.u >> 16) & 1u)) >> 16;
    return (unsigned short)r;
}

__device__ __forceinline__ unsigned cvtpk(float a, float b) {
    unsigned r;
    asm("v_cvt_pk_bf16_f32 %0, %1, %2" : "=v"(r) : "v"(a), "v"(b));
    return r;
}

__device__ __forceinline__ void mfma16(f32x4& d, short8 a, short8 b) {
    asm("v_mfma_f32_16x16x32_bf16 %0, %1, %2, %0" : "+v"(d) : "v"(a), "v"(b));
}

// q pre-scale: 1/sqrt(64) * log2(e) -> softmax via exp2
#define QSCALE 0.18033688011112042f

// ---------------- fused fp32 -> bf16 convert (x, w_in, w_out in one launch) ----------------
#define XN4 2097152
#define WIN4 786432
#define WOUT4 262144
__global__ __launch_bounds__(256) void cvt_all(const float* __restrict__ x,
                                               const float* __restrict__ w_in,
                                               const float* __restrict__ w_out,
                                               unsigned short* __restrict__ xb,
                                               unsigned short* __restrict__ winb,
                                               unsigned short* __restrict__ woutb) {
    int idx = blockIdx.x * 256 + threadIdx.x;
    int stride = gridDim.x * 256;
    for (int i = idx; i < XN4 + WIN4 + WOUT4; i += stride) {
        const float4* src;
        ushort4* dst;
        int j;
        if (i < XN4) {
            src = (const float4*)x; dst = (ushort4*)xb; j = i;
        } else if (i < XN4 + WIN4) {
            src = (const float4*)w_in; dst = (ushort4*)winb; j = i - XN4;
        } else {
            src = (const float4*)w_out; dst = (ushort4*)woutb; j = i - XN4 - WIN4;
        }
        float4 v = src[j];
        ushort4 o;
        o.x = f2bf(v.x); o.y = f2bf(v.y); o.z = f2bf(v.z); o.w = f2bf(v.w);
        dst[j] = o;
    }
}

// ---------------- 128x128 NT GEMM (round-7/8 proven, unchanged) ----------------
template <int EPI>
__global__ __launch_bounds__(256) void gemm_nt(
    const unsigned short* __restrict__ A, const unsigned short* __restrict__ B,
    const float* __restrict__ bias, int M, int N, int K,
    float* __restrict__ Cf, unsigned short* __restrict__ qb,
    unsigned short* __restrict__ kb, unsigned short* __restrict__ vtb) {
    __shared__ unsigned short As[128 * 64];
    __shared__ unsigned short Bs[128 * 64];
    const int tid = threadIdx.x;
    const int lane = tid & 63;
    const int wv = tid >> 6;
    const int wm = (wv >> 1) * 64, wn = (wv & 1) * 64;
    const int lr = lane & 15, lg = lane >> 4;
    const int x7 = lr & 7;
    const int m0 = blockIdx.x * 128, n0 = blockIdx.y * 128;

    f32x4 acc[4][4];
#pragma unroll
    for (int i = 0; i < 4; i++)
#pragma unroll
        for (int j = 0; j < 4; j++) acc[i][j] = (f32x4){0.f, 0.f, 0.f, 0.f};

    const int sr = tid >> 3;
    const int sc = ((tid & 7) ^ ((tid >> 3) & 7)) * 8;
    const unsigned short* Ag = A + (size_t)(m0 + sr) * K + sc;
    const unsigned short* Bg = B + (size_t)(n0 + sr) * K + sc;
    unsigned short* Asl = As + tid * 8;
    unsigned short* Bsl = Bs + tid * 8;

    for (int kt = 0; kt < K; kt += 64) {
        __syncthreads();
#pragma unroll
        for (int i = 0; i < 4; i++) {
            gload16(Ag + (size_t)(i * 32) * K + kt, Asl + i * 2048);
            gload16(Bg + (size_t)(i * 32) * K + kt, Bsl + i * 2048);
        }
        __syncthreads();
#pragma unroll
        for (int ks = 0; ks < 2; ks++) {
            short8 af[4], bf[4];
#pragma unroll
            for (int mi = 0; mi < 4; mi++)
                af[mi] = *(const short8*)(As + (wm + mi * 16 + lr) * 64 +
                                          (((ks * 4 + lg) ^ x7) * 8));
#pragma unroll
            for (int ni = 0; ni < 4; ni++)
                bf[ni] = *(const short8*)(Bs + (wn + ni * 16 + lr) * 64 +
                                          (((ks * 4 + lg) ^ x7) * 8));
            __builtin_amdgcn_s_setprio(1);
#pragma unroll
            for (int mi = 0; mi < 4; mi++)
#pragma unroll
                for (int ni = 0; ni < 4; ni++) mfma16(acc[mi][ni], af[mi], bf[ni]);
            __builtin_amdgcn_s_setprio(0);
        }
    }

    // ---------------- epilogue ----------------
#pragma unroll
    for (int ni = 0; ni < 4; ni++) {
        const int col = n0 + wn + ni * 16 + lr;
        const float bia = bias[col];
        const unsigned h = (unsigned)col / 192u;
        const int rem = col - (int)h * 192;
        const int tq = rem >> 6, d = rem & 63;
#pragma unroll
        for (int mi = 0; mi < 4; mi++) {
            const int row = m0 + wm + mi * 16 + lg * 4;
            if (EPI == 1) {
#pragma unroll
                for (int r = 0; r < 4; r++)
                    Cf[(size_t)(row + r) * N + col] = acc[mi][ni][r] + bia;
            } else {
                const int bb = row >> 10, s = row & 1023;
                const int bh = bb * 16 + (int)h;
                if (tq == 0) {
#pragma unroll
                    for (int r = 0; r < 4; r++)
                        qb[((size_t)bh * 1024 + s + r) * 64 + d] =
                            f2bf((acc[mi][ni][r] + bia) * QSCALE);
                } else if (tq == 1) {
#pragma unroll
                    for (int r = 0; r < 4; r++)
                        kb[((size_t)bh * 1024 + s + r) * 64 + d] = f2bf(acc[mi][ni][r] + bia);
                } else {
                    uint2 pk;
                    pk.x = cvtpk(acc[mi][ni][0] + bia, acc[mi][ni][1] + bia);
                    pk.y = cvtpk(acc[mi][ni][2] + bia, acc[mi][ni][3] + bia);
                    *(uint2*)(vtb + ((size_t)bh * 64 + d) * 1024 + s) = pk;
                }
            }
        }
    }
}

// ---------------- flash attention: K/V double-buffer, 1 barrier/tile, stage-ahead ----------------
__device__ __forceinline__ void softmax_half(f32x4 (&s)[4], float& m, float& l,
                                             f32x4 (&o)[4], unsigned short* pbuf,
                                             int lr, int lg, int x7) {
    float mx = s[0][0];
#pragma unroll
    for (int kt = 0; kt < 4; kt++)
#pragma unroll
        for (int r = 0; r < 4; r++) mx = fmaxf(mx, s[kt][r]);
    mx = fmaxf(mx, __shfl_xor(mx, 16));
    mx = fmaxf(mx, __shfl_xor(mx, 32));
    const float mn = fmaxf(m, mx);
    const float alpha = __builtin_amdgcn_exp2f(m - mn);
    m = mn;
    float p[4][4];
    float rs = 0.f;
#pragma unroll
    for (int kt = 0; kt < 4; kt++)
#pragma unroll
        for (int r = 0; r < 4; r++) {
            p[kt][r] = __builtin_amdgcn_exp2f(s[kt][r] - mn);
            rs += p[kt][r];
        }
    rs += __shfl_xor(rs, 16);
    rs += __shfl_xor(rs, 32);
    l = l * alpha + rs;
#pragma unroll
    for (int mi = 0; mi < 4; mi++)
#pragma unroll
        for (int r = 0; r < 4; r++) o[mi][r] *= alpha;
#pragma unroll
    for (int kt = 0; kt < 4; kt++)
#pragma unroll
        for (int w2 = 0; w2 < 2; w2++) {
            const unsigned pk = cvtpk(p[kt][2 * w2], p[kt][2 * w2 + 1]);
            const int col = (kt * 16 + lg * 4 + 2 * w2) ^ (x7 << 3);
            *(unsigned*)(pbuf + lr * 64 + col) = pk;
        }
}

__global__ __launch_bounds__(256) void attn_fwd(
    const unsigned short* __restrict__ qg, const unsigned short* __restrict__ kg,
    const unsigned short* __restrict__ vtg, unsigned short* __restrict__ vals) {
    __shared__ unsigned short Ks[2][64 * 64];
    __shared__ unsigned short Vts[2][64 * 64];
    __shared__ unsigned short Ps[4 * 2048];
    const int tid = threadIdx.x, lane = tid & 63, w = tid >> 6;
    const int lr = lane & 15, lg = lane >> 4;
    const int x7 = lr & 7;
    // grid = (128 bh, 8 qblk): bid%8 = bh%8 -> all q-blocks of a bh on one XCD (KV L2-local).
    const int bh = blockIdx.x;
    const int q0 = blockIdx.y * 128 + w * 32;

    const unsigned short* qrowA = qg + ((size_t)bh * 1024 + q0 + lr) * 64;
    const unsigned short* qrowB = qrowA + 16 * 64;
    short8 qA[2], qB[2];
    qA[0] = *(const short8*)(qrowA + lg * 8);
    qA[1] = *(const short8*)(qrowA + 32 + lg * 8);
    qB[0] = *(const short8*)(qrowB + lg * 8);
    qB[1] = *(const short8*)(qrowB + 32 + lg * 8);

    f32x4 oA[4], oB[4];
    float mA = -1e30f, mB = -1e30f, lA = 0.f, lB = 0.f;
#pragma unroll
    for (int i = 0; i < 4; i++) {
        oA[i] = (f32x4){0.f, 0.f, 0.f, 0.f};
        oB[i] = (f32x4){0.f, 0.f, 0.f, 0.f};
    }

    const unsigned short* kb = kg + (size_t)bh * 65536;
    const unsigned short* vb = vtg + (size_t)bh * 65536;
    unsigned short* pwl = Ps + w * 2048;

    const int srow = tid >> 3;
    const int scol = ((tid & 7) ^ (srow & 7)) * 8;

    // stage one 64-kv tile into buffer `buf`
    auto stage = [&](int kv0, int buf) {
#pragma unroll
        for (int i = 0; i < 2; i++) {
            gload16(kb + (size_t)(kv0 + i * 32 + srow) * 64 + scol,
                    &Ks[buf][i * 2048 + tid * 8]);
            gload16(vb + (size_t)(i * 32 + srow) * 1024 + kv0 + scol,
                    &Vts[buf][i * 2048 + tid * 8]);
        }
    };

    stage(0, 0);
    __syncthreads();  // implicit vmcnt(0) drain: tile 0 staged

    for (int t = 0; t < 16; ++t) {
        const int buf = t & 1;
        // issue next tile's loads first: latency hides under QK+softmax+PV.
        // buf^1 was last read in tile t-1, whose end-barrier has passed -> safe.
        if (t < 15) stage((t + 1) * 64, buf ^ 1);
        const unsigned short* Kb = Ks[buf];
        const unsigned short* Vb = Vts[buf];

        f32x4 sA[4], sB[4];
#pragma unroll
        for (int i = 0; i < 4; i++) {
            sA[i] = (f32x4){0.f, 0.f, 0.f, 0.f};
            sB[i] = (f32x4){0.f, 0.f, 0.f, 0.f};
        }
#pragma unroll
        for (int kt = 0; kt < 4; kt++) {
            const short8 k0 = *(const short8*)(Kb + (kt * 16 + lr) * 64 + ((0 + lg) ^ x7) * 8);
            const short8 k1 = *(const short8*)(Kb + (kt * 16 + lr) * 64 + ((4 + lg) ^ x7) * 8);
            __builtin_amdgcn_s_setprio(1);
            mfma16(sA[kt], k0, qA[0]);
            mfma16(sB[kt], k0, qB[0]);
            mfma16(sA[kt], k1, qA[1]);
            mfma16(sB[kt], k1, qB[1]);
            __builtin_amdgcn_s_setprio(0);
        }

        softmax_half(sA, mA, lA, oA, pwl, lr, lg, x7);
        softmax_half(sB, mB, lB, oB, pwl + 1024, lr, lg, x7);

        short8 pA[2], pB[2];
#pragma unroll
        for (int ks2 = 0; ks2 < 2; ks2++) {
            pA[ks2] = *(const short8*)(pwl + lr * 64 + (((ks2 * 4 + lg) ^ x7) * 8));
            pB[ks2] = *(const short8*)(pwl + 1024 + lr * 64 + (((ks2 * 4 + lg) ^ x7) * 8));
        }
#pragma unroll
        for (int mi = 0; mi < 4; mi++) {
            const short8 v0 = *(const short8*)(Vb + (mi * 16 + lr) * 64 + ((0 + lg) ^ x7) * 8);
            const short8 v1 = *(const short8*)(Vb + (mi * 16 + lr) * 64 + ((4 + lg) ^ x7) * 8);
            __builtin_amdgcn_s_setprio(1);
            mfma16(oA[mi], v0, pA[0]);
            mfma16(oB[mi], v0, pB[0]);
            mfma16(oA[mi], v1, pA[1]);
            mfma16(oB[mi], v1, pB[1]);
            __builtin_amdgcn_s_setprio(0);
        }

        // single barrier per tile (implicit vmcnt(0)+lgkmcnt(0) drain: stage loads
        // for t+1 have had the whole compute phase to land -> near-free).
        __syncthreads();
    }

    const int bb = bh >> 4, hh = bh & 15;
    {
        const float inv = 1.f / lA;
        unsigned short* vp = vals + (size_t)(bb * 1024 + q0 + lr) * 1024 + hh * 64 + lg * 4;
#pragma unroll
        for (int mi = 0; mi < 4; mi++) {
            uint2 st;
            st.x = cvtpk(oA[mi][0] * inv, oA[mi][1] * inv);
            st.y = cvtpk(oA[mi][2] * inv, oA[mi][3] * inv);
            *(uint2*)(vp + mi * 16) = st;
        }
    }
    {
        const float inv = 1.f / lB;
        unsigned short* vp = vals + (size_t)(bb * 1024 + q0 + 16 + lr) * 1024 + hh * 64 + lg * 4;
#pragma unroll
        for (int mi = 0; mi < 4; mi++) {
            uint2 st;
            st.x = cvtpk(oB[mi][0] * inv, oB[mi][1] * inv);
            st.y = cvtpk(oB[mi][2] * inv, oB[mi][3] * inv);
            *(uint2*)(vp + mi * 16) = st;
        }
    }
}

extern "C" void kernel_launch(void* const* d_in, const int* in_sizes, int n_in,
                              void* d_out, int out_size, void* d_ws, size_t ws_size,
                              hipStream_t stream) {
    const float* x = (const float*)d_in[0];
    const float* w_in = (const float*)d_in[1];
    const float* b_in = (const float*)d_in[2];
    const float* w_out = (const float*)d_in[3];
    const float* b_out = (const float*)d_in[4];
    float* out = (float*)d_out;

    unsigned short* ws = (unsigned short*)d_ws;
    unsigned short* xb = ws;                   // 8388608  (reused as vals)
    unsigned short* winb = xb + 8388608;       // 3145728
    unsigned short* woutb = winb + 3145728;    // 1048576
    unsigned short* qb = woutb + 1048576;      // 8388608  (Q [bh,1024,64], pre-scaled)
    unsigned short* kb = qb + 8388608;         // 8388608
    unsigned short* vtb = kb + 8388608;        // 8388608  (V^T [bh,64,1024])
    unsigned short* vals = xb;                 // alias

    cvt_all<<<2048, 256, 0, stream>>>(x, w_in, w_out, xb, winb, woutb);

    gemm_nt<0><<<dim3(64, 24), 256, 0, stream>>>(xb, winb, b_in, 8192, 3072, 1024,
                                                 nullptr, qb, kb, vtb);
    attn_fwd<<<dim3(128, 8), 256, 0, stream>>>(qb, kb, vtb, vals);
    gemm_nt<1><<<dim3(64, 8), 256, 0, stream>>>(vals, woutb, b_out, 8192, 1024, 1024,
                                                out, nullptr, nullptr, nullptr);
}